// Round 1
// baseline (170.422 us; speedup 1.0000x reference)
//
#include <hip/hip_runtime.h>
#include <hip/hip_bf16.h>

typedef __attribute__((ext_vector_type(16))) float f32x16;
typedef __attribute__((ext_vector_type(8)))  short s16x8;

#define NB    64
#define CH    64
#define TS    2048
#define QBLK  128
#define KVB   64

__device__ __forceinline__ unsigned f2bf(float f) {
    unsigned u = __float_as_uint(f);
    return (u + 0x7fffu + ((u >> 16) & 1u)) >> 16;   // RNE f32 -> bf16 bits
}

__global__ __launch_bounds__(256, 2)
void qkv_attn_kernel(const float* __restrict__ qkv, float* __restrict__ out)
{
    // LDS: rows are 64 bf16 = 128 B; 16B-block XOR swizzle by (row&7)<<4
    __shared__ __align__(16) char q_sm[QBLK * 128];
    __shared__ __align__(16) char k_sm[KVB * 128];
    __shared__ __align__(16) char v_sm[CH * 128];

    const int tid  = threadIdx.x;
    const int lane = tid & 63;
    const int wv   = tid >> 6;
    const int col  = lane & 31;   // MFMA col lane -> t within wave tile
    const int hi   = lane >> 5;

    // XCD-grouped mapping: dispatch D -> XCD D&7; give each XCD 128
    // consecutive logical blocks => all 16 q-tiles of a batch share an XCD/L2.
    const int Dd      = (int)blockIdx.x;
    const int logical = (Dd & 7) * 128 + (Dd >> 3);
    const int b  = logical >> 4;
    const int qt = logical & 15;
    const int t0 = qt * QBLK;

    const float* __restrict__ qb = qkv + (size_t)b * (3 * CH) * TS;

    // ---- stage Q tile transposed: q_sm[t][c] (bf16)
    {
        const int tq  = tid & 127;
        const int c2b = tid >> 7;
        #pragma unroll
        for (int j = 0; j < 16; ++j) {
            const int c2 = c2b + 2 * j;          // dword column (2 channels)
            const int c  = 2 * c2;
            const float f0 = qb[(size_t)c * TS + t0 + tq];
            const float f1 = qb[(size_t)(c + 1) * TS + t0 + tq];
            const unsigned pk = f2bf(f0) | (f2bf(f1) << 16);
            *(unsigned*)(q_sm + tq * 128 + ((4 * c2) ^ ((tq & 7) << 4))) = pk;
        }
    }
    __syncthreads();

    // hoist Q fragments (B operand: col = t, k = c), reused over all kv tiles
    s16x8 qfrag[4];
    {
        const int tq = wv * 32 + col;
        #pragma unroll
        for (int ks = 0; ks < 4; ++ks)
            qfrag[ks] = *(const s16x8*)(q_sm + tq * 128 +
                          ((32 * ks + 16 * hi) ^ ((tq & 7) << 4)));
    }

    f32x16 oacc0, oacc1;
    #pragma unroll
    for (int i = 0; i < 16; ++i) { oacc0[i] = 0.f; oacc1[i] = 0.f; }
    float m_run = -3.0e38f, l_run = 0.f;

    for (int kt = 0; kt < TS / KVB; ++kt) {
        const int s0 = kt * KVB;
        __syncthreads();                 // previous tile's compute done
        // ---- stage K transposed: k_sm[s][c]
        {
            const int sk  = tid & 63;
            const int c2b = tid >> 6;
            #pragma unroll
            for (int j = 0; j < 8; ++j) {
                const int c2 = c2b + 4 * j;
                const int c  = 2 * c2;
                const float f0 = qb[(size_t)(CH + c) * TS + s0 + sk];
                const float f1 = qb[(size_t)(CH + c + 1) * TS + s0 + sk];
                const unsigned pk = f2bf(f0) | (f2bf(f1) << 16);
                *(unsigned*)(k_sm + sk * 128 + ((4 * c2) ^ ((sk & 7) << 4))) = pk;
            }
        }
        // ---- stage V native: v_sm[c][s]
        {
            const int sb = tid & 15;
            const int c0 = tid >> 4;
            #pragma unroll
            for (int j = 0; j < 4; ++j) {
                const int c = c0 + 16 * j;
                const float* src = qb + (size_t)(2 * CH + c) * TS + s0 + 4 * sb;
                const unsigned pka = f2bf(src[0]) | (f2bf(src[1]) << 16);
                const unsigned pkb = f2bf(src[2]) | (f2bf(src[3]) << 16);
                const int off = c * 128 + ((8 * sb) ^ ((c & 7) << 4));
                *(unsigned*)(v_sm + off)     = pka;
                *(unsigned*)(v_sm + off + 4) = pkb;
            }
        }
        __syncthreads();

        // ---- swapped QK^T: S^T[s, t] = sum_c K[c,s] * Q[c,t]
        f32x16 sa0, sa1;
        #pragma unroll
        for (int i = 0; i < 16; ++i) { sa0[i] = 0.f; sa1[i] = 0.f; }
        #pragma unroll
        for (int ks = 0; ks < 4; ++ks) {
            const int sw = 32 * ks + 16 * hi;
            const s16x8 kf0 = *(const s16x8*)(k_sm + col * 128        + (sw ^ ((col & 7) << 4)));
            const s16x8 kf1 = *(const s16x8*)(k_sm + (32 + col) * 128 + (sw ^ ((col & 7) << 4)));
            sa0 = __builtin_amdgcn_mfma_f32_32x32x16_bf16(kf0, qfrag[ks], sa0, 0, 0, 0);
            sa1 = __builtin_amdgcn_mfma_f32_32x32x16_bf16(kf1, qfrag[ks], sa1, 0, 0, 0);
        }

        // ---- online softmax over s; per-lane row t = col (both halves same t)
        float p0[16], p1[16];
        float mh = -3.0e38f;
        #pragma unroll
        for (int r = 0; r < 16; ++r) {
            p0[r] = sa0[r] * 0.125f;     // scale^2 = 1/sqrt(ch)
            p1[r] = sa1[r] * 0.125f;
            mh = fmaxf(mh, fmaxf(p0[r], p1[r]));
        }
        mh = fmaxf(mh, __shfl_xor(mh, 32));
        const float mnew = fmaxf(m_run, mh);
        const float corr = __expf(m_run - mnew);
        float sum = 0.f;
        #pragma unroll
        for (int r = 0; r < 16; ++r) {
            p0[r] = __expf(p0[r] - mnew);
            p1[r] = __expf(p1[r] - mnew);
            sum += p0[r] + p1[r];
        }
        sum += __shfl_xor(sum, 32);
        l_run = l_run * corr + sum;
        m_run = mnew;
        #pragma unroll
        for (int i = 0; i < 16; ++i) { oacc0[i] *= corr; oacc1[i] *= corr; }

        // ---- pack P rows to bf16 pairs (own half's s-values)
        unsigned pq0[8], pq1[8];
        #pragma unroll
        for (int q = 0; q < 8; ++q) {
            pq0[q] = f2bf(p0[2*q]) | (f2bf(p0[2*q+1]) << 16);
            pq1[q] = f2bf(p1[2*q]) | (f2bf(p1[2*q+1]) << 16);
        }

        // ---- PV: O^T[c, t] += V * P^T  (exchange halves to build B-frag)
        #pragma unroll
        for (int ks = 0; ks < 4; ++ks) {
            const int base = (ks & 1) * 4;
            unsigned a0, a1, a2, a3;
            if (ks < 2) { a0 = pq0[base]; a1 = pq0[base+1]; a2 = pq0[base+2]; a3 = pq0[base+3]; }
            else        { a0 = pq1[base]; a1 = pq1[base+1]; a2 = pq1[base+2]; a3 = pq1[base+3]; }
            const unsigned y0 = __shfl_xor(a2, 32);
            const unsigned y1 = __shfl_xor(a3, 32);
            const unsigned y2 = __shfl_xor(a0, 32);
            const unsigned y3 = __shfl_xor(a1, 32);
            union { unsigned u[4]; s16x8 v; } pb;
            pb.u[0] = hi ? y0 : a0;
            pb.u[1] = hi ? y1 : a1;
            pb.u[2] = hi ? a2 : y2;
            pb.u[3] = hi ? a3 : y3;
            const int sw = 32 * ks + 16 * hi;
            const s16x8 vf0 = *(const s16x8*)(v_sm + col * 128        + (sw ^ ((col & 7) << 4)));
            const s16x8 vf1 = *(const s16x8*)(v_sm + (32 + col) * 128 + (sw ^ (((32 + col) & 7) << 4)));
            oacc0 = __builtin_amdgcn_mfma_f32_32x32x16_bf16(vf0, pb.v, oacc0, 0, 0, 0);
            oacc1 = __builtin_amdgcn_mfma_f32_32x32x16_bf16(vf1, pb.v, oacc1, 0, 0, 0);
        }
    }

    // ---- epilogue: normalize rows and store out[b][c][t]
    const float inv = 1.0f / l_run;
    float* __restrict__ ob = out + (size_t)b * CH * TS;
    const int t = t0 + wv * 32 + col;
    #pragma unroll
    for (int r = 0; r < 16; ++r) {
        const int c = (r & 3) + 8 * (r >> 2) + 4 * hi;
        ob[(size_t)c * TS + t]        = oacc0[r] * inv;
        ob[(size_t)(c + 32) * TS + t] = oacc1[r] * inv;
    }
}

extern "C" void kernel_launch(void* const* d_in, const int* in_sizes, int n_in,
                              void* d_out, int out_size, void* d_ws, size_t ws_size,
                              hipStream_t stream) {
    const float* qkv = (const float*)d_in[0];
    float* outp      = (float*)d_out;
    const int nblocks = NB * (TS / QBLK);   // 64 * 16 = 1024
    qkv_attn_kernel<<<dim3(nblocks), dim3(256), 0, stream>>>(qkv, outp);
}

// Round 2
// 128.992 us; speedup vs baseline: 1.3212x; 1.3212x over previous
//
#include <hip/hip_runtime.h>
#include <hip/hip_bf16.h>

typedef __attribute__((ext_vector_type(16))) float f32x16;
typedef __attribute__((ext_vector_type(8)))  short s16x8;

#define NB    64
#define CH    64
#define TS    2048
#define QBLK  128
#define KVB   64
#define NKV   (TS / KVB)
// workspace layout (bf16): Qt [b][t][c] | Kt [b][s][c] | V [b][c][s]
#define KT_OFF  (16u * 1024 * 1024)
#define V_OFF   (32u * 1024 * 1024)
#define BSTRIDE (TS * CH * 2)          // 262144 B per batch per region
// fold full softmax scale (1/8) and log2(e) into Q so scores are exp2-domain
#define QSCALE  0.18033688011112042f   // 0.125 * log2(e)

__device__ __forceinline__ unsigned f2bf(float f) {
    unsigned u = __float_as_uint(f);
    return (u + 0x7fffu + ((u >> 16) & 1u)) >> 16;   // RNE f32 -> bf16 bits
}
__device__ __forceinline__ unsigned cvtpk(float lo, float hi) {
    unsigned r;
    asm("v_cvt_pk_bf16_f32 %0, %1, %2" : "=v"(r) : "v"(lo), "v"(hi));
    return r;
}
__device__ __forceinline__ float exp2a(float x) {
    float r;
    asm("v_exp_f32 %0, %1" : "=v"(r) : "v"(x));
    return r;
}
__device__ __forceinline__ void gload16(const void* g, void* l) {
    __builtin_amdgcn_global_load_lds(
        (const __attribute__((address_space(1))) void*)g,
        (__attribute__((address_space(3))) void*)l, 16, 0, 0);
}

// ---- pre-pass: transpose+convert Q (scaled) and K to bf16 [b][t|s][c]
__global__ __launch_bounds__(256)
void prep_qk(const float* __restrict__ qkv, char* __restrict__ ws)
{
    __shared__ float tile[64][65];
    const int bid   = (int)blockIdx.x;
    const int b     = bid >> 6;
    const int rt    = bid & 63;
    const int which = rt >> 5;          // 0 = Q, 1 = K
    const int tt    = rt & 31;          // 64-wide t/s tile
    const float* src = qkv + ((size_t)b * 192 + which * 64) * TS + tt * 64;

    const int c  = threadIdx.x >> 2;
    const int tq = (threadIdx.x & 3) * 16;
    const float4* s4 = (const float4*)(src + (size_t)c * TS + tq);
    #pragma unroll
    for (int j = 0; j < 4; ++j) {
        const float4 f = s4[j];
        tile[c][tq + 4*j + 0] = f.x;
        tile[c][tq + 4*j + 1] = f.y;
        tile[c][tq + 4*j + 2] = f.z;
        tile[c][tq + 4*j + 3] = f.w;
    }
    __syncthreads();

    const int t  = threadIdx.x >> 2;
    const int cq = (threadIdx.x & 3) * 16;
    const float sc = which ? 1.0f : QSCALE;
    unsigned pk[8];
    #pragma unroll
    for (int j = 0; j < 8; ++j) {
        const float f0 = tile[cq + 2*j][t] * sc;
        const float f1 = tile[cq + 2*j + 1][t] * sc;
        pk[j] = f2bf(f0) | (f2bf(f1) << 16);
    }
    char* dst = ws + (which ? KT_OFF : 0u) +
                (size_t)b * BSTRIDE + ((size_t)tt * 64 + t) * 128 + cq * 2;
    ((uint4*)dst)[0] = make_uint4(pk[0], pk[1], pk[2], pk[3]);
    ((uint4*)dst)[1] = make_uint4(pk[4], pk[5], pk[6], pk[7]);
}

// ---- pre-pass: convert V to bf16, layout preserved [b][c][s]
__global__ __launch_bounds__(256)
void prep_v(const float* __restrict__ qkv, char* __restrict__ ws)
{
    const size_t e   = ((size_t)blockIdx.x * 256 + threadIdx.x) * 16;
    const int b      = (int)(e >> 17);             // 64*2048 = 2^17 elems/batch
    const size_t rem = e & 131071;
    const float4* src = (const float4*)(qkv + (size_t)b * 393216 + 262144 + rem);
    unsigned pk[8];
    #pragma unroll
    for (int j = 0; j < 4; ++j) {
        const float4 f = src[j];
        pk[2*j]     = f2bf(f.x) | (f2bf(f.y) << 16);
        pk[2*j + 1] = f2bf(f.z) | (f2bf(f.w) << 16);
    }
    char* dst = ws + V_OFF + e * 2;
    ((uint4*)dst)[0] = make_uint4(pk[0], pk[1], pk[2], pk[3]);
    ((uint4*)dst)[1] = make_uint4(pk[4], pk[5], pk[6], pk[7]);
}

__global__ __launch_bounds__(256, 4)
void qkv_attn_kernel(const char* __restrict__ ws, float* __restrict__ out)
{
    // double-buffered K/V tiles; rows are 128 B, XOR-swizzled by (row&7)<<4
    // (swizzle realized via per-lane GLOBAL source addr; LDS dest is linear)
    __shared__ __align__(16) char k_sm[2][KVB * 128];
    __shared__ __align__(16) char v_sm[2][CH * 128];

    const int tid  = threadIdx.x;
    const int lane = tid & 63;
    const int wv   = tid >> 6;
    const int col  = lane & 31;
    const int hi   = lane >> 5;

    // XCD-grouped mapping: all 16 q-tiles of a batch share an XCD's L2
    const int Dd      = (int)blockIdx.x;
    const int logical = (Dd & 7) * 128 + (Dd >> 3);
    const int b  = logical >> 4;
    const int qt = logical & 15;
    const int t0 = qt * QBLK;

    const char* qtb = ws + (size_t)b * BSTRIDE;
    const char* ktb = ws + KT_OFF + (size_t)b * BSTRIDE;
    const char* vtb = ws + V_OFF  + (size_t)b * BSTRIDE;

    // ---- Q fragments straight from global (B operand: col = t, k = c)
    s16x8 qfrag[4];
    {
        const int t = t0 + wv * 32 + col;
        const char* qrow = qtb + (size_t)t * 128 + hi * 16;
        #pragma unroll
        for (int ks = 0; ks < 4; ++ks)
            qfrag[ks] = *(const s16x8*)(qrow + ks * 32);
    }

    // ---- per-lane staging source addresses (XOR pre-swizzled)
    const int lr = lane >> 3, lx = lane & 7;
    const int krow = wv * 16 + lr;                       // also V channel
    const unsigned koff = krow * 128  + ((lx ^ (krow & 7)) << 4);
    const unsigned voff = krow * 4096 + ((lx ^ (krow & 7)) << 4);
    const char* ksrc = ktb + koff;     // +8192/tile, +1024 chunk2
    const char* vsrc = vtb + voff;     // +128/tile,  +32768 chunk2
    char* kd0 = k_sm[0] + wv * 2048;
    char* vd0 = v_sm[0] + wv * 2048;
    char* kd1 = k_sm[1] + wv * 2048;
    char* vd1 = v_sm[1] + wv * 2048;

    f32x16 oacc0, oacc1;
    #pragma unroll
    for (int i = 0; i < 16; ++i) { oacc0[i] = 0.f; oacc1[i] = 0.f; }
    float m_run = -3.0e38f, l_run = 0.f;

    // prologue: stage tile 0 into buf 0
    gload16(ksrc, kd0);           gload16(ksrc + 1024, kd0 + 1024);
    gload16(vsrc, vd0);           gload16(vsrc + 32768, vd0 + 1024);
    __syncthreads();

    int cur = 0;
    for (int kt = 0; kt < NKV; ++kt) {
        // issue next tile's loads into the other buffer (overlaps compute)
        if (kt + 1 < NKV) {
            const char* kp = ksrc + (size_t)(kt + 1) * 8192;
            const char* vp = vsrc + (size_t)(kt + 1) * 128;
            char* kd = cur ? kd0 : kd1;
            char* vd = cur ? vd0 : vd1;
            gload16(kp, kd);          gload16(kp + 1024, kd + 1024);
            gload16(vp, vd);          gload16(vp + 32768, vd + 1024);
        }
        const char* kb = k_sm[cur];
        const char* vb = v_sm[cur];

        // ---- swapped QK^T: S^T[s, t] = sum_c K[c,s] * Q[c,t]  (exp2 domain)
        f32x16 sa0, sa1;
        #pragma unroll
        for (int i = 0; i < 16; ++i) { sa0[i] = 0.f; sa1[i] = 0.f; }
        #pragma unroll
        for (int ks = 0; ks < 4; ++ks) {
            const int sw = 32 * ks + 16 * hi;
            const s16x8 kf0 = *(const s16x8*)(kb + col * 128        + (sw ^ ((col & 7) << 4)));
            const s16x8 kf1 = *(const s16x8*)(kb + (32 + col) * 128 + (sw ^ ((col & 7) << 4)));
            sa0 = __builtin_amdgcn_mfma_f32_32x32x16_bf16(kf0, qfrag[ks], sa0, 0, 0, 0);
            sa1 = __builtin_amdgcn_mfma_f32_32x32x16_bf16(kf1, qfrag[ks], sa1, 0, 0, 0);
        }

        // ---- online softmax with defer-max (T13); row t = col in both halves
        float mh = -3.0e38f;
        #pragma unroll
        for (int r = 0; r < 16; ++r) mh = fmaxf(mh, fmaxf(sa0[r], sa1[r]));
        mh = fmaxf(mh, __shfl_xor(mh, 32));
        if (!__all(mh - m_run <= 8.0f)) {
            const float mnew = fmaxf(m_run, mh);
            const float corr = exp2a(m_run - mnew);
            #pragma unroll
            for (int i = 0; i < 16; ++i) { oacc0[i] *= corr; oacc1[i] *= corr; }
            l_run *= corr;
            m_run = mnew;
        }
        float p0[16], p1[16];
        float sum = 0.f;
        #pragma unroll
        for (int r = 0; r < 16; ++r) {
            p0[r] = exp2a(sa0[r] - m_run);
            p1[r] = exp2a(sa1[r] - m_run);
            sum += p0[r] + p1[r];
        }
        l_run += sum;   // per-half l; halves combined in epilogue

        // ---- P -> bf16 pairs (T12: one cvt_pk per pair)
        unsigned pq0[8], pq1[8];
        #pragma unroll
        for (int q = 0; q < 8; ++q) {
            pq0[q] = cvtpk(p0[2*q], p0[2*q + 1]);
            pq1[q] = cvtpk(p1[2*q], p1[2*q + 1]);
        }

        // ---- PV: O^T[c, t] += V * P^T  (exchange halves to build B-frag)
        #pragma unroll
        for (int ks = 0; ks < 4; ++ks) {
            const int base = (ks & 1) * 4;
            unsigned a0, a1, a2, a3;
            if (ks < 2) { a0 = pq0[base]; a1 = pq0[base+1]; a2 = pq0[base+2]; a3 = pq0[base+3]; }
            else        { a0 = pq1[base]; a1 = pq1[base+1]; a2 = pq1[base+2]; a3 = pq1[base+3]; }
            const unsigned y0 = __shfl_xor(a2, 32);
            const unsigned y1 = __shfl_xor(a3, 32);
            const unsigned y2 = __shfl_xor(a0, 32);
            const unsigned y3 = __shfl_xor(a1, 32);
            union { unsigned u[4]; s16x8 v; } pb;
            pb.u[0] = hi ? y0 : a0;
            pb.u[1] = hi ? y1 : a1;
            pb.u[2] = hi ? a2 : y2;
            pb.u[3] = hi ? a3 : y3;
            const int sw = 32 * ks + 16 * hi;
            const s16x8 vf0 = *(const s16x8*)(vb + col * 128        + (sw ^ ((col & 7) << 4)));
            const s16x8 vf1 = *(const s16x8*)(vb + (32 + col) * 128 + (sw ^ ((col & 7) << 4)));
            oacc0 = __builtin_amdgcn_mfma_f32_32x32x16_bf16(vf0, pb.v, oacc0, 0, 0, 0);
            oacc1 = __builtin_amdgcn_mfma_f32_32x32x16_bf16(vf1, pb.v, oacc1, 0, 0, 0);
        }
        __syncthreads();   // waits prefetch (vmcnt) + all reads of cur done
        cur ^= 1;
    }

    // ---- epilogue: combine half-sums, normalize, store out[b][c][t]
    const float l_tot = l_run + __shfl_xor(l_run, 32);
    const float inv = 1.0f / l_tot;
    float* __restrict__ ob = out + (size_t)b * CH * TS;
    const int t = t0 + wv * 32 + col;
    #pragma unroll
    for (int r = 0; r < 16; ++r) {
        const int c = (r & 3) + 8 * (r >> 2) + 4 * hi;
        ob[(size_t)c * TS + t]        = oacc0[r] * inv;
        ob[(size_t)(c + 32) * TS + t] = oacc1[r] * inv;
    }
}

extern "C" void kernel_launch(void* const* d_in, const int* in_sizes, int n_in,
                              void* d_out, int out_size, void* d_ws, size_t ws_size,
                              hipStream_t stream) {
    const float* qkv = (const float*)d_in[0];
    float* outp      = (float*)d_out;
    char* ws         = (char*)d_ws;            // needs 48 MB
    prep_qk<<<dim3(NB * 64), dim3(256), 0, stream>>>(qkv, ws);   // 64 b * 32 tiles * 2 (Q,K)
    prep_v <<<dim3(2048),    dim3(256), 0, stream>>>(qkv, ws);
    qkv_attn_kernel<<<dim3(NB * (TS / QBLK)), dim3(256), 0, stream>>>(ws, outp);
}